// Round 2
// baseline (41.019 us; speedup 1.0000x reference)
//
#include <hip/hip_runtime.h>

// predictions: [B=64, T=8192, D=64] f32 ; start_timestamp: int32 scalar (device)
// loss = sum_{b, j in [s,s+L), d} (p[b,j+1,d]-p[b,j,d])^2 / B - 0.5
// L = 4096, INHERENT_NEIGHBORHOOD = 0.5

#define BATCH 64
#define TDIM  8192
#define DDIM  64
#define LWIN  4096

#define D4        16                 // float4 per row
#define WIN4      (LWIN * D4)        // 65536 float4 per-batch window
#define WIN4_LOG2 16
#define TD4       (TDIM * D4)        // 131072 float4 per-batch full span

#define NBLOCKS  2048
#define NTHREADS 256
#define TOTAL4   (BATCH * WIN4)                      // 4,194,304
#define PER_THR  (TOTAL4 / (NBLOCKS * NTHREADS))     // exactly 8

__global__ __launch_bounds__(NTHREADS) void nl_kernel(
    const float4* __restrict__ pred, const int* __restrict__ s_ptr,
    float* __restrict__ out) {
    const int s = *s_ptr;
    const int base = blockIdx.x * NTHREADS + threadIdx.x;

    float acc = 0.0f;
    #pragma unroll
    for (int i = 0; i < PER_THR; ++i) {
        const int v  = base + i * (NBLOCKS * NTHREADS);
        const int b  = v >> WIN4_LOG2;               // v / 65536
        const int r  = v & (WIN4 - 1);               // v % 65536
        const int a4 = b * TD4 + s * D4 + r;
        const float4 p0 = pred[a4];
        const float4 p1 = pred[a4 + D4];             // row j+1: L1/L2 hit (same wave's p0)
        const float dx = p1.x - p0.x;
        const float dy = p1.y - p0.y;
        const float dz = p1.z - p0.z;
        const float dw = p1.w - p0.w;
        acc += dx * dx + dy * dy + dz * dz + dw * dw;
    }

    // wave64 reduce
    #pragma unroll
    for (int off = 32; off > 0; off >>= 1) acc += __shfl_down(acc, off, 64);

    __shared__ float smem[NTHREADS / 64];
    const int lane = threadIdx.x & 63;
    const int wid  = threadIdx.x >> 6;
    if (lane == 0) smem[wid] = acc;
    __syncthreads();
    if (threadIdx.x == 0) {
        const float bs = smem[0] + smem[1] + smem[2] + smem[3];
        // out accumulates: total/BATCH - 0.5, spread over blocks (0.5/2048 = 2^-12 exact)
        atomicAdd(out, bs * (1.0f / BATCH) - 0.5f / NBLOCKS);
    }
}

extern "C" void kernel_launch(void* const* d_in, const int* in_sizes, int n_in,
                              void* d_out, int out_size, void* d_ws, size_t ws_size,
                              hipStream_t stream) {
    const float4* pred = (const float4*)d_in[0];
    const int* s_ptr   = (const int*)d_in[1];
    float* out         = (float*)d_out;

    hipMemsetAsync(d_out, 0, sizeof(float), stream);   // graph-capturable async fill
    nl_kernel<<<NBLOCKS, NTHREADS, 0, stream>>>(pred, s_ptr, out);
}

// Round 3
// 17.597 us; speedup vs baseline: 2.3311x; 2.3311x over previous
//
#include <hip/hip_runtime.h>

// predictions: [B=64, T=8192, D=64] f32 ; start_timestamp: int32 scalar (device)
// loss = sum_{b, j in [s,s+L), d} (p[b,j+1,d]-p[b,j,d])^2 / B - 0.5
// L = 4096, INHERENT_NEIGHBORHOOD = 0.5

#define BATCH 64
#define TDIM  8192
#define DDIM  64
#define LWIN  4096

#define D4    16                     // float4 per row
#define TD4   (TDIM * D4)            // 131072 float4 per-batch full span

#define RCHAIN 8                     // rows per thread chain: 9 loads -> 8 diffs
#define NTHREADS 256
#define NCHAINS  (LWIN / RCHAIN)     // 512 chains per (b, column)
#define TOTTHR   (BATCH * D4 * NCHAINS)   // 64*16*512 = 524288 threads
#define NBLOCKS  (TOTTHR / NTHREADS)      // 2048

__global__ __launch_bounds__(NTHREADS) void nl_partial_kernel(
    const float4* __restrict__ pred, const int* __restrict__ s_ptr,
    float* __restrict__ partial) {
    const int s   = *s_ptr;
    const int tid = blockIdx.x * NTHREADS + threadIdx.x;
    const int c    = tid & 15;          // float4 column within row
    const int g    = tid >> 4;          // chain id
    const int jblk = g & (NCHAINS - 1); // row-block within window
    const int b    = g >> 9;            // batch  (NCHAINS = 512 = 2^9)

    const float4* p = pred + ((size_t)b * TD4 + (size_t)(s + jblk * RCHAIN) * D4 + c);

    // load 9 consecutive rows' float4 at column c (all independent -> full MLP)
    float4 a[RCHAIN + 1];
    #pragma unroll
    for (int i = 0; i <= RCHAIN; ++i) a[i] = p[i * D4];

    float acc = 0.0f;
    #pragma unroll
    for (int i = 0; i < RCHAIN; ++i) {
        const float dx = a[i + 1].x - a[i].x;
        const float dy = a[i + 1].y - a[i].y;
        const float dz = a[i + 1].z - a[i].z;
        const float dw = a[i + 1].w - a[i].w;
        acc += dx * dx + dy * dy + dz * dz + dw * dw;
    }

    // wave64 reduce
    #pragma unroll
    for (int off = 32; off > 0; off >>= 1) acc += __shfl_down(acc, off, 64);

    __shared__ float smem[NTHREADS / 64];
    const int lane = threadIdx.x & 63;
    const int wid  = threadIdx.x >> 6;
    if (lane == 0) smem[wid] = acc;
    __syncthreads();
    if (threadIdx.x == 0)
        partial[blockIdx.x] = smem[0] + smem[1] + smem[2] + smem[3];
}

__global__ __launch_bounds__(NTHREADS) void nl_final_kernel(
    const float* __restrict__ partial, float* __restrict__ out) {
    float acc = 0.0f;
    #pragma unroll
    for (int i = 0; i < NBLOCKS / NTHREADS; ++i)
        acc += partial[threadIdx.x + i * NTHREADS];

    #pragma unroll
    for (int off = 32; off > 0; off >>= 1) acc += __shfl_down(acc, off, 64);

    __shared__ float smem[NTHREADS / 64];
    const int lane = threadIdx.x & 63;
    const int wid  = threadIdx.x >> 6;
    if (lane == 0) smem[wid] = acc;
    __syncthreads();
    if (threadIdx.x == 0) {
        const float total = smem[0] + smem[1] + smem[2] + smem[3];
        out[0] = total * (1.0f / BATCH) - 0.5f;   // INHERENT_NEIGHBORHOOD
    }
}

extern "C" void kernel_launch(void* const* d_in, const int* in_sizes, int n_in,
                              void* d_out, int out_size, void* d_ws, size_t ws_size,
                              hipStream_t stream) {
    const float4* pred = (const float4*)d_in[0];
    const int* s_ptr   = (const int*)d_in[1];
    float* out         = (float*)d_out;
    float* partial     = (float*)d_ws;            // NBLOCKS floats = 8 KB

    nl_partial_kernel<<<NBLOCKS, NTHREADS, 0, stream>>>(pred, s_ptr, partial);
    nl_final_kernel<<<1, NTHREADS, 0, stream>>>(partial, out);
}